// Round 1
// baseline (655.370 us; speedup 1.0000x reference)
//
#include <hip/hip_runtime.h>
#include <hip/hip_bf16.h>
#include <hip/hip_cooperative_groups.h>

namespace cg = cooperative_groups;

// ---------------------------------------------------------------------------
// 2-layer GraphConv (DGL norm='both') + mean_nodes pool + linear classifier.
// N=80000, E=1.28M, D=H=64, C=5, G=512.
// R12: fuse the ENTIRE 7-kernel pipeline into one cooperative kernel with
// grid.sync() between stages. Theory: sum-of-parts (BW+VALU+atomics) models
// ~100-130us of the 224us; the remaining ~100us is 8 serialized dispatch
// boundaries (launch latency + drain + L2 flush), all on the critical path.
// Each stage's internal structure is transplanted VERBATIM from R11 (only
// control-flow wrapping: guards instead of early returns, grid-stride vbs,
// shared-mem union). Bonus: the fused kernel (>44us) finally surfaces in the
// rocprof top-5 with whole-pipeline counters.
// ---------------------------------------------------------------------------

#define NBK 160            // max buckets: ceil(80000/512)=157 <= 160
#define HB  256            // edge-pass virtual blocks in stage A
#define CAP 9216           // per-bucket slot capacity (mean 8192, +11 sigma)

typedef __attribute__((ext_vector_type(8))) short bf16x8;
typedef __attribute__((ext_vector_type(4))) float f32x4;

__device__ __forceinline__ float bflo(unsigned u) { return __uint_as_float(u << 16); }
__device__ __forceinline__ float bfhi(unsigned u) { return __uint_as_float(u & 0xffff0000u); }
__device__ __forceinline__ float bf1(unsigned short u) { return __uint_as_float((unsigned)u << 16); }
__device__ __forceinline__ unsigned short f2bf(float f) {   // RNE
    unsigned u = __float_as_uint(f);
    return (unsigned short)((u + 0x7fff + ((u >> 16) & 1)) >> 16);
}
__device__ __forceinline__ unsigned packbf(float lo, float hi) {
    return (unsigned)f2bf(lo) | ((unsigned)f2bf(hi) << 16);
}

// --- agg stage: pure gather-sum with next-node prefetch (R11 verbatim) -----
__device__ __forceinline__ void agg_body(
    const unsigned short* __restrict__ zin, unsigned short* __restrict__ yout,
    const int* __restrict__ cols, const int* __restrict__ row_offs,
    const int* __restrict__ deg, int N)
{
    int lane = threadIdx.x & 63;
    int sub  = lane >> 3;
    int li   = lane & 7;
    const uint4* x4 = (const uint4*)zin;

    int wid = (blockIdx.x * 256 + threadIdx.x) >> 6;
    int nw  = (gridDim.x * 256) >> 6;

    int ro = 0, cnt = 0, idx = 0;
    if (wid < N) {
        ro = row_offs[wid];
        cnt = deg[wid];
        if (lane < min(cnt, 64)) idx = cols[ro + lane];
    }
    for (int node = wid; node < N; node += nw) {
        int nnode = node + nw;
        int nro = 0, ncnt = 0;
        if (nnode < N) { nro = row_offs[nnode]; ncnt = deg[nnode]; }  // prefetch

        float a0=0.f,a1=0.f,a2=0.f,a3=0.f,a4=0.f,a5=0.f,a6=0.f,a7=0.f;
        int cc = 0;
        int cidx = idx;
        while (cc < cnt) {
            int m = min(cnt - cc, 64);
            for (int i = 0; i < m; i += 32) {
                int e1 = i + sub, e2 = i + 8 + sub, e3 = i + 16 + sub, e4 = i + 24 + sub;
                int s1 = __shfl(cidx, min(e1, m - 1));
                int s2 = __shfl(cidx, min(e2, m - 1));
                int s3 = __shfl(cidx, min(e3, m - 1));
                int s4 = __shfl(cidx, min(e4, m - 1));
                uint4 v1 = make_uint4(0u,0u,0u,0u), v2 = v1, v3 = v1, v4 = v1;
                if (e1 < m) v1 = x4[(size_t)s1 * 8 + li];
                if (e2 < m) v2 = x4[(size_t)s2 * 8 + li];
                if (e3 < m) v3 = x4[(size_t)s3 * 8 + li];
                if (e4 < m) v4 = x4[(size_t)s4 * 8 + li];
                a0 += bflo(v1.x); a1 += bfhi(v1.x);
                a2 += bflo(v1.y); a3 += bfhi(v1.y);
                a4 += bflo(v1.z); a5 += bfhi(v1.z);
                a6 += bflo(v1.w); a7 += bfhi(v1.w);
                a0 += bflo(v2.x); a1 += bfhi(v2.x);
                a2 += bflo(v2.y); a3 += bfhi(v2.y);
                a4 += bflo(v2.z); a5 += bfhi(v2.z);
                a6 += bflo(v2.w); a7 += bfhi(v2.w);
                a0 += bflo(v3.x); a1 += bfhi(v3.x);
                a2 += bflo(v3.y); a3 += bfhi(v3.y);
                a4 += bflo(v3.z); a5 += bfhi(v3.z);
                a6 += bflo(v3.w); a7 += bfhi(v3.w);
                a0 += bflo(v4.x); a1 += bfhi(v4.x);
                a2 += bflo(v4.y); a3 += bfhi(v4.y);
                a4 += bflo(v4.z); a5 += bfhi(v4.z);
                a6 += bflo(v4.w); a7 += bfhi(v4.w);
            }
            cc += 64;
            if (cc < cnt) cidx = (lane < min(cnt - cc, 64)) ? cols[ro + cc + lane] : 0;
        }
        // prefetch next node's col during the reduce
        idx = 0;
        if (nnode < N && lane < min(ncnt, 64)) idx = cols[nro + lane];

        #pragma unroll
        for (int off = 8; off <= 32; off <<= 1) {
            a0 += __shfl_xor(a0, off); a1 += __shfl_xor(a1, off);
            a2 += __shfl_xor(a2, off); a3 += __shfl_xor(a3, off);
            a4 += __shfl_xor(a4, off); a5 += __shfl_xor(a5, off);
            a6 += __shfl_xor(a6, off); a7 += __shfl_xor(a7, off);
        }
        if (sub == 0) {                       // 8 lanes store the 128B row
            uint4 o;
            o.x = packbf(a0, a1);
            o.y = packbf(a2, a3);
            o.z = packbf(a4, a5);
            o.w = packbf(a6, a7);
            ((uint4*)yout)[(size_t)node * 8 + li] = o;
        }
        ro = nro; cnt = ncnt;
    }
}

// --- gemm stage: Z[m] = relu(ndst[m]*(S[m]@W) + b) [* nsrc[m]] -------------
// R11 verbatim, except: W-fragment load hoisted above a grid-stride tile loop,
// early return -> continue (cooperative kernel: all threads must reach sync).
__device__ __forceinline__ void gemm_body(
    const unsigned short* __restrict__ A, const float* __restrict__ W,
    const float* __restrict__ bb, const float* __restrict__ ndst,
    const float* __restrict__ nsrc, unsigned short* __restrict__ Z,
    int M, int scale_out)
{
    int t = threadIdx.x, lane = t & 63, w4 = t >> 6;
    int cl = lane & 15, quad = lane >> 4;
    bf16x8 bfrag[4][2];
    #pragma unroll
    for (int nt = 0; nt < 4; nt++)
        #pragma unroll
        for (int ks = 0; ks < 2; ks++)
            #pragma unroll
            for (int j = 0; j < 8; j++)
                bfrag[nt][ks][j] =
                    (short)f2bf(W[(ks * 32 + quad * 8 + j) * 64 + nt * 16 + cl]);
    float bias[4];
    #pragma unroll
    for (int nt = 0; nt < 4; nt++) bias[nt] = bb[nt * 16 + cl];

    int ntiles = (M + 63) >> 6;
    for (int tb = blockIdx.x; tb < ntiles; tb += gridDim.x) {
        int mbase = tb * 64 + w4 * 16;
        if (mbase >= M) continue;
        int row = min(mbase + cl, M - 1);
        const uint4* a4 = (const uint4*)A;
        union { uint4 u; bf16x8 v; } a0, a1;
        a0.u = a4[(size_t)row * 8 + quad];
        a1.u = a4[(size_t)row * 8 + 4 + quad];

        float nd[4], ns[4];
        #pragma unroll
        for (int r = 0; r < 4; r++) {
            int m = min(mbase + quad * 4 + r, M - 1);
            nd[r] = ndst[m];
            ns[r] = scale_out ? nsrc[m] : 1.f;
        }

        #pragma unroll
        for (int nt = 0; nt < 4; nt++) {
            f32x4 acc = {0.f, 0.f, 0.f, 0.f};
            acc = __builtin_amdgcn_mfma_f32_16x16x32_bf16(a0.v, bfrag[nt][0], acc, 0, 0, 0);
            acc = __builtin_amdgcn_mfma_f32_16x16x32_bf16(a1.v, bfrag[nt][1], acc, 0, 0, 0);
            #pragma unroll
            for (int r = 0; r < 4; r++) {
                int m = mbase + quad * 4 + r;
                if (m < M)
                    Z[(size_t)m * 64 + nt * 16 + cl] =
                        f2bf(fmaxf(nd[r] * acc[r] + bias[nt], 0.f) * ns[r]);
            }
        }
    }
}

// --- the whole pipeline as one cooperative kernel --------------------------
__global__ __launch_bounds__(256, 4) void fused_all(
    const float* __restrict__ h, const int* __restrict__ src,
    const int* __restrict__ dst, const int* __restrict__ gids,
    const float* __restrict__ W1, const float* __restrict__ b1,
    const float* __restrict__ W2, const float* __restrict__ b2,
    const float* __restrict__ Wc, const float* __restrict__ bc,
    float* __restrict__ out,
    int* curD, int* curS, int* row_offs, int* deg,
    float* nsrc, float* ndst, int* goffs, int* pack,
    unsigned short* sloc, int* cols,
    unsigned short* xs, unsigned short* sb1, unsigned short* h1s,
    int N, int E, int G, int NB)
{
    cg::grid_group gg = cg::this_grid();
    __shared__ int smem[1040];          // union: A: hd[160]+hs[160]; B: hist[512]+nsl[512]+wt[4]; G: red[256]
    const int t = threadIdx.x;
    const int NBB = (N + 255) >> 8;

    // ================= stage A: bucket scatter + graph bounds ==============
    for (int vb = blockIdx.x; vb < HB + NBB; vb += gridDim.x) {
        if (vb >= HB) {                  // fused bounds
            int i = (vb - HB) * 256 + t;
            if (i < N) {
                int b = gids[i];
                if (i == 0) {
                    for (int g = 0; g <= b; g++) goffs[g] = 0;
                } else {
                    int a = gids[i - 1];
                    for (int g = a + 1; g <= b; g++) goffs[g] = i;
                }
                if (i == N - 1) {
                    for (int g = b + 1; g <= G; g++) goffs[g] = N;
                }
            }
        } else {
            int* hd = smem;
            int* hs = smem + NBK;
            for (int i = t; i < NB; i += 256) { hd[i] = 0; hs[i] = 0; }
            __syncthreads();
            int chunk = (E + HB - 1) / HB;
            int s0 = vb * chunk, se = min(E, s0 + chunk);
            int q0 = s0 >> 2, q1 = se >> 2;          // s0 is 4-aligned (chunk%4==0)
            const int4* s4 = (const int4*)src;
            const int4* d4 = (const int4*)dst;
            for (int q = q0 + t; q < q1; q += 256) {
                int4 d = d4[q];
                int4 s = s4[q];
                atomicAdd(&hd[d.x >> 9], 1); atomicAdd(&hd[d.y >> 9], 1);
                atomicAdd(&hd[d.z >> 9], 1); atomicAdd(&hd[d.w >> 9], 1);
                atomicAdd(&hs[s.x >> 9], 1); atomicAdd(&hs[s.y >> 9], 1);
                atomicAdd(&hs[s.z >> 9], 1); atomicAdd(&hs[s.w >> 9], 1);
            }
            for (int i = (q1 << 2) + t; i < se; i += 256) {   // tail
                atomicAdd(&hd[dst[i] >> 9], 1);
                atomicAdd(&hs[src[i] >> 9], 1);
            }
            __syncthreads();
            for (int b = t; b < NB; b += 256) {      // reserve global slots
                int cd = hd[b], cs = hs[b];
                hd[b] = cd ? atomicAdd(&curD[b], cd) : 0;
                hs[b] = cs ? atomicAdd(&curS[b], cs) : 0;
            }
            __syncthreads();
            for (int q = q0 + t; q < q1; q += 256) {
                int4 d = d4[q];
                int4 s = s4[q];
                #pragma unroll
                for (int j = 0; j < 4; j++) {
                    int ss = j == 0 ? s.x : j == 1 ? s.y : j == 2 ? s.z : s.w;
                    int dd = j == 0 ? d.x : j == 1 ? d.y : j == 2 ? d.z : d.w;
                    int bd = dd >> 9, bs = ss >> 9;
                    int pd = atomicAdd(&hd[bd], 1);
                    int ps = atomicAdd(&hs[bs], 1);
                    if (pd < CAP) pack[(size_t)bd * CAP + pd] = ((dd & 511) << 17) | ss;
                    if (ps < CAP) sloc[(size_t)bs * CAP + ps] = (unsigned short)(ss & 511);
                }
            }
            for (int i = (q1 << 2) + t; i < se; i += 256) {   // tail
                int s = src[i], d = dst[i];
                int bd = d >> 9, bs = s >> 9;
                int pd = atomicAdd(&hd[bd], 1);
                int ps = atomicAdd(&hs[bs], 1);
                if (pd < CAP) pack[(size_t)bd * CAP + pd] = ((d & 511) << 17) | s;
                if (ps < CAP) sloc[(size_t)bs * CAP + ps] = (unsigned short)(s & 511);
            }
            __syncthreads();             // protect smem across vb iterations
        }
    }
    gg.sync();

    // ================= stage B: CSR build + nsrc prescale ==================
    for (int vb = blockIdx.x; vb < 2 * NB; vb += gridDim.x) {
        int* hist = smem;
        float* nsl = (float*)(smem + 512);
        int* wt = smem + 1024;
        bool dmode = vb < NB;
        int b = dmode ? vb : vb - NB;
        int n0 = b << 9, n1 = min(N, n0 + 512);
        hist[t] = 0; hist[t + 256] = 0;
        __syncthreads();
        int e0 = b * CAP;
        int tot = min(dmode ? curD[b] : curS[b], CAP);
        int e1 = e0 + tot;
        if (!dmode) {
            for (int i = e0 + t; i < e1; i += 256)
                atomicAdd(&hist[sloc[i]], 1);
            __syncthreads();
            for (int n = n0 + t; n < n1; n += 256) {
                float sc = rsqrtf((float)max(hist[n - n0], 1));
                nsrc[n] = sc;
                nsl[n - n0] = sc;
            }
            __syncthreads();
            int cnt = n1 - n0;
            const float2* h2p = (const float2*)h;
            ushort2* xp = (ushort2*)xs;
            for (int i = t; i < cnt * 32; i += 256) {
                int node = i >> 5;
                float sc = nsl[node];
                float2 v = h2p[(size_t)(n0 + node) * 32 + (i & 31)];
                ushort2 o;
                o.x = f2bf(v.x * sc);
                o.y = f2bf(v.y * sc);
                xp[(size_t)(n0 + node) * 32 + (i & 31)] = o;
            }
        } else {
            for (int i = e0 + t; i < e1; i += 256)
                atomicAdd(&hist[pack[i] >> 17], 1);
            __syncthreads();
            int c0 = hist[2 * t], c1 = hist[2 * t + 1];
            int v = c0 + c1;
            int lane = t & 63, w4 = t >> 6;
            int x = v;
            #pragma unroll
            for (int off = 1; off < 64; off <<= 1) {
                int y = __shfl_up(x, off);
                if (lane >= off) x += y;
            }
            if (lane == 63) wt[w4] = x;
            __syncthreads();
            int bw = 0;
            for (int i = 0; i < w4; i++) bw += wt[i];
            int excl = x - v + bw;
            int n = n0 + 2 * t;
            if (n < n1) {
                row_offs[n] = e0 + excl;
                deg[n] = c0;
                ndst[n] = rsqrtf((float)max(c0, 1));
            }
            if (n + 1 < n1) {
                row_offs[n + 1] = e0 + excl + c0;
                deg[n + 1] = c1;
                ndst[n + 1] = rsqrtf((float)max(c1, 1));
            }
            hist[2 * t] = excl;
            hist[2 * t + 1] = excl + c0;
            __syncthreads();
            for (int i = e0 + t; i < e1; i += 256) {
                int wd = pack[i];
                int pos = atomicAdd(&hist[wd >> 17], 1);
                cols[e0 + pos] = wd & 0x1FFFF;
            }
        }
        __syncthreads();                 // protect smem across vb iterations
    }
    gg.sync();

    // ================= layer 1 =============================================
    agg_body(xs, sb1, cols, row_offs, deg, N);
    gg.sync();
    gemm_body(sb1, W1, b1, ndst, nsrc, h1s, N, 1);
    gg.sync();

    // ================= layer 2 =============================================
    agg_body(h1s, sb1, cols, row_offs, deg, N);   // sb1 reused as s2
    gg.sync();
    gemm_body(sb1, W2, b2, ndst, nsrc, xs, N, 0); // xs reused as h2
    gg.sync();

    // ================= stage G: mean pool + classifier =====================
    const unsigned short* h2 = xs;
    for (int g = blockIdx.x; g < G; g += gridDim.x) {
        int lane = t & 63;
        int w4 = t >> 6;
        int s = goffs[g], e = goffs[g + 1];
        float acc = 0.f;
        for (int i = s + w4; i < e; i += 4) acc += bf1(h2[(size_t)i * 64 + lane]);
        float* red = (float*)smem;
        red[w4 * 64 + lane] = acc;
        __syncthreads();
        if (w4 == 0) {
            float tot = red[0 * 64 + lane] + red[1 * 64 + lane] +
                        red[2 * 64 + lane] + red[3 * 64 + lane];
            float mean = tot / (float)max(e - s, 1);
            float wc[5];
            #pragma unroll
            for (int c = 0; c < 5; c++) wc[c] = Wc[lane * 5 + c];
            #pragma unroll
            for (int c = 0; c < 5; c++) {
                float p = mean * wc[c];
                #pragma unroll
                for (int off = 32; off; off >>= 1) p += __shfl_down(p, off);
                if (lane == 0) out[g * 5 + c] = p + bc[c];
            }
        }
        __syncthreads();                 // protect smem across g iterations
    }
}

extern "C" void kernel_launch(void* const* d_in, const int* in_sizes, int n_in,
                              void* d_out, int out_size, void* d_ws, size_t ws_size,
                              hipStream_t stream)
{
    const float* h    = (const float*)d_in[0];
    const int*   src  = (const int*)d_in[1];
    const int*   dst  = (const int*)d_in[2];
    const int*   gids = (const int*)d_in[3];
    const float* W1   = (const float*)d_in[4];
    const float* b1   = (const float*)d_in[5];
    const float* W2   = (const float*)d_in[6];
    const float* b2   = (const float*)d_in[7];
    const float* Wc   = (const float*)d_in[8];
    const float* bc   = (const float*)d_in[9];
    float* out = (float*)d_out;

    int N = in_sizes[0] / 64;
    int E = in_sizes[1];
    int G = out_size / 5;
    int NB = (N + 511) >> 9;

    auto align = [](size_t x) { return (x + 255) & ~(size_t)255; };
    char* p = (char*)d_ws;
    int* curD    = (int*)p;            p += align((size_t)2 * NBK * 4);
    int* curS    = curD + NBK;
    int* row_offs= (int*)p;            p += align((size_t)N * 4);
    int* deg     = (int*)p;            p += align((size_t)N * 4);
    float* nsrc  = (float*)p;          p += align((size_t)N * 4);
    float* ndst  = (float*)p;          p += align((size_t)N * 4);
    int* goffs   = (int*)p;            p += align((size_t)(G + 1) * 4);
    int* pack    = (int*)p;            p += align((size_t)NBK * CAP * 4);
    unsigned short* sloc = (unsigned short*)p; p += align((size_t)NBK * CAP * 2);
    int* cols    = (int*)p;            p += align((size_t)NBK * CAP * 4);
    unsigned short* xs  = (unsigned short*)p; p += align((size_t)N * 64 * 2);
    unsigned short* sb1 = (unsigned short*)p; p += align((size_t)N * 64 * 2);
    unsigned short* h1s = (unsigned short*)p; p += align((size_t)N * 64 * 2);

    // co-residency: query once; __launch_bounds__(256,4) targets 4 blocks/CU.
    static int grid_blocks = 0;
    if (grid_blocks == 0) {
        int perCU = 0;
        if (hipOccupancyMaxActiveBlocksPerMultiprocessor(&perCU, fused_all, 256, 0)
                != hipSuccess || perCU < 1)
            perCU = 2;                   // conservative fallback
        grid_blocks = perCU * 256;       // 256 CUs on MI355X
        if (grid_blocks > 2048) grid_blocks = 2048;
    }

    hipMemsetAsync(curD, 0, (size_t)2 * NBK * 4, stream);

    void* args[] = { &h, &src, &dst, &gids, &W1, &b1, &W2, &b2, &Wc, &bc, &out,
                     &curD, &curS, &row_offs, &deg, &nsrc, &ndst, &goffs, &pack,
                     &sloc, &cols, &xs, &sb1, &h1s, &N, &E, &G, &NB };
    hipLaunchCooperativeKernel((void*)fused_all, dim3(grid_blocks), dim3(256),
                               args, 0, stream);
}

// Round 2
// 337.793 us; speedup vs baseline: 1.9402x; 1.9402x over previous
//
#include <hip/hip_runtime.h>
#include <hip/hip_bf16.h>

// ---------------------------------------------------------------------------
// 2-layer GraphConv (DGL norm='both') + mean_nodes pool + linear classifier.
// N=80000, E=1.28M, D=H=64, C=5, G=512.
// R13: R12's cooperative mega-fusion was a 3x LOSS (1080us, all pipes idle:
// HBM 2.9%, VALU 5%) -- grid.sync() on 8-XCD MI355X costs ~150us each
// (device-scope fence + L2 drain). REVERT to the R11 7-kernel skeleton, and
// instead fuse only the barrier-FREE boundaries:
//  (a) gemm is row-local => fold the 64x64 GEMV into the agg wave epilogue
//      (W in 16KB LDS; after the xor-reduce every lane holds the aggregated
//      vector as 8 f32, replicated 8x across subs => 64 shfl-bcast + 64
//      ds_read + 64 FMA per node, hidden under gather latency). Kills the
//      s1/s2 intermediates (40MB) and both MFMA gemm dispatches.
//  (b) pool is a segment-sum => layer-2 epilogue atomicAdd's its row into a
//      128KB per-graph f32 accumulator (~156-way contention over 32K addrs).
//      Kills the h2 materialization + pool read (20MB). Tiny cls kernel ends.
// pA_scatter / p5_build are R11-verbatim.
// ---------------------------------------------------------------------------

#define NBK 160            // max buckets: ceil(80000/512)=157 <= 160
#define HB  256            // edge-pass blocks in pA
#define CAP 9216           // per-bucket slot capacity (mean 8192, +11 sigma)

typedef __attribute__((ext_vector_type(8))) short bf16x8;
typedef __attribute__((ext_vector_type(4))) float f32x4;

__device__ __forceinline__ float bflo(unsigned u) { return __uint_as_float(u << 16); }
__device__ __forceinline__ float bfhi(unsigned u) { return __uint_as_float(u & 0xffff0000u); }
__device__ __forceinline__ float bf1(unsigned short u) { return __uint_as_float((unsigned)u << 16); }
__device__ __forceinline__ unsigned short f2bf(float f) {   // RNE
    unsigned u = __float_as_uint(f);
    return (unsigned short)((u + 0x7fff + ((u >> 16) & 1)) >> 16);
}

// --- pA: single-pass bucket scatter (blocks < HB) + graph bounds (rest) ----
__global__ __launch_bounds__(256) void pA_scatter(
    const int* __restrict__ src, const int* __restrict__ dst,
    int* __restrict__ curD, int* __restrict__ curS,       // NBK cursors each, pre-zeroed
    int* __restrict__ pack, unsigned short* __restrict__ sloc,
    const int* __restrict__ gids, int* __restrict__ goffs,
    int E, int NB, int N, int G)
{
    if (blockIdx.x >= HB) {                  // fused bounds_kernel
        int i = (blockIdx.x - HB) * 256 + threadIdx.x;
        if (i >= N) return;
        int b = gids[i];
        if (i == 0) {
            for (int g = 0; g <= b; g++) goffs[g] = 0;
        } else {
            int a = gids[i - 1];
            for (int g = a + 1; g <= b; g++) goffs[g] = i;
        }
        if (i == N - 1) {
            for (int g = b + 1; g <= G; g++) goffs[g] = N;
        }
        return;
    }
    __shared__ int hd[NBK], hs[NBK];
    int t = threadIdx.x;
    for (int i = t; i < NB; i += 256) { hd[i] = 0; hs[i] = 0; }
    __syncthreads();
    int chunk = (E + HB - 1) / HB;
    int s0 = blockIdx.x * chunk, s1 = min(E, s0 + chunk);
    // vectorized histogram pass
    int q0 = s0 >> 2, q1 = s1 >> 2;          // s0 is 4-aligned (chunk%4==0)
    const int4* s4 = (const int4*)src;
    const int4* d4 = (const int4*)dst;
    for (int q = q0 + t; q < q1; q += 256) {
        int4 d = d4[q];
        int4 s = s4[q];
        atomicAdd(&hd[d.x >> 9], 1); atomicAdd(&hd[d.y >> 9], 1);
        atomicAdd(&hd[d.z >> 9], 1); atomicAdd(&hd[d.w >> 9], 1);
        atomicAdd(&hs[s.x >> 9], 1); atomicAdd(&hs[s.y >> 9], 1);
        atomicAdd(&hs[s.z >> 9], 1); atomicAdd(&hs[s.w >> 9], 1);
    }
    for (int i = (q1 << 2) + t; i < s1; i += 256) {   // tail
        atomicAdd(&hd[dst[i] >> 9], 1);
        atomicAdd(&hs[src[i] >> 9], 1);
    }
    __syncthreads();
    for (int b = t; b < NB; b += 256) {      // reserve global slots
        int cd = hd[b], cs = hs[b];
        hd[b] = cd ? atomicAdd(&curD[b], cd) : 0;   // device atomic, 1/bucket
        hs[b] = cs ? atomicAdd(&curS[b], cs) : 0;
    }
    __syncthreads();
    // vectorized scatter pass (chunk re-read is L2-hot)
    for (int q = q0 + t; q < q1; q += 256) {
        int4 d = d4[q];
        int4 s = s4[q];
        #pragma unroll
        for (int j = 0; j < 4; j++) {
            int ss = j == 0 ? s.x : j == 1 ? s.y : j == 2 ? s.z : s.w;
            int dd = j == 0 ? d.x : j == 1 ? d.y : j == 2 ? d.z : d.w;
            int bd = dd >> 9, bs = ss >> 9;
            int pd = atomicAdd(&hd[bd], 1);  // LDS atomic
            int ps = atomicAdd(&hs[bs], 1);  // LDS atomic
            if (pd < CAP) pack[(size_t)bd * CAP + pd] = ((dd & 511) << 17) | ss;
            if (ps < CAP) sloc[(size_t)bs * CAP + ps] = (unsigned short)(ss & 511);
        }
    }
    for (int i = (q1 << 2) + t; i < s1; i += 256) {   // tail
        int s = src[i], d = dst[i];
        int bd = d >> 9, bs = s >> 9;
        int pd = atomicAdd(&hd[bd], 1);
        int ps = atomicAdd(&hs[bs], 1);
        if (pd < CAP) pack[(size_t)bd * CAP + pd] = ((d & 511) << 17) | s;
        if (ps < CAP) sloc[(size_t)bs * CAP + ps] = (unsigned short)(s & 511);
    }
}

// --- p5: dst mode -> CSR (row_offs,deg,col,ndst); src mode -> nsrc+prescale -
__global__ __launch_bounds__(256) void p5_build(
    const int* __restrict__ pack, const unsigned short* __restrict__ sloc,
    const int* __restrict__ curD, const int* __restrict__ curS,
    int* __restrict__ col, int* __restrict__ row_offs, int* __restrict__ deg,
    float* __restrict__ nsrc, float* __restrict__ ndst,
    const float* __restrict__ h, unsigned short* __restrict__ xs,
    int N, int NB)
{
    __shared__ int hist[512];
    __shared__ float nsl[512];
    __shared__ int wt[4];
    int t = threadIdx.x;
    bool dmode = blockIdx.x < NB;
    int b = dmode ? blockIdx.x : blockIdx.x - NB;
    int n0 = b << 9, n1 = min(N, n0 + 512);
    hist[t] = 0; hist[t + 256] = 0;
    __syncthreads();
    int e0 = b * CAP;
    int tot = min(dmode ? curD[b] : curS[b], CAP);
    int e1 = e0 + tot;
    if (!dmode) {
        for (int i = e0 + t; i < e1; i += 256)
            atomicAdd(&hist[sloc[i]], 1);            // LDS atomic
        __syncthreads();
        for (int n = n0 + t; n < n1; n += 256) {
            float s = rsqrtf((float)max(hist[n - n0], 1));
            nsrc[n] = s;
            nsl[n - n0] = s;
        }
        __syncthreads();
        int cnt = n1 - n0;
        const float2* h2p = (const float2*)h;
        ushort2* xp = (ushort2*)xs;
        for (int i = t; i < cnt * 32; i += 256) {
            int node = i >> 5;
            float s = nsl[node];
            float2 v = h2p[(size_t)(n0 + node) * 32 + (i & 31)];
            ushort2 o;
            o.x = f2bf(v.x * s);
            o.y = f2bf(v.y * s);
            xp[(size_t)(n0 + node) * 32 + (i & 31)] = o;
        }
        return;
    }
    for (int i = e0 + t; i < e1; i += 256)
        atomicAdd(&hist[pack[i] >> 17], 1);          // LDS atomic
    __syncthreads();
    int c0 = hist[2 * t], c1 = hist[2 * t + 1];
    int v = c0 + c1;
    int lane = t & 63, w = t >> 6;
    int x = v;
    #pragma unroll
    for (int off = 1; off < 64; off <<= 1) {
        int y = __shfl_up(x, off);
        if (lane >= off) x += y;
    }
    if (lane == 63) wt[w] = x;
    __syncthreads();
    int bw = 0;
    for (int i = 0; i < w; i++) bw += wt[i];
    int excl = x - v + bw;
    int n = n0 + 2 * t;
    if (n < n1) {
        row_offs[n] = e0 + excl;
        deg[n] = c0;
        ndst[n] = rsqrtf((float)max(c0, 1));
    }
    if (n + 1 < n1) {
        row_offs[n + 1] = e0 + excl + c0;
        deg[n + 1] = c1;
        ndst[n + 1] = rsqrtf((float)max(c1, 1));
    }
    hist[2 * t] = excl;
    hist[2 * t + 1] = excl + c0;
    __syncthreads();
    for (int i = e0 + t; i < e1; i += 256) {
        int wd = pack[i];
        int pos = atomicAdd(&hist[wd >> 17], 1);     // LDS atomic
        col[e0 + pos] = wd & 0x1FFFF;
    }
}

// --- fused gather-sum + row-local 64x64 GEMV epilogue ----------------------
// MODE 0: yout[node] = bf16(relu(nd*(s@W)+b) * ns)       (layer 1)
// MODE 1: atomicAdd(gacc[gids[node]], relu(nd*(s@W)+b))  (layer 2 + pool)
template<int MODE>
__global__ __launch_bounds__(256) void agg_gemv(
    const unsigned short* __restrict__ zin, unsigned short* __restrict__ yout,
    const int* __restrict__ cols, const int* __restrict__ row_offs,
    const int* __restrict__ deg, const float* __restrict__ W,
    const float* __restrict__ bias, const float* __restrict__ ndst,
    const float* __restrict__ nsrc, const int* __restrict__ gids,
    float* __restrict__ gacc, int N)
{
    __shared__ float Wl[4096];                 // W row-major [64][64], 16KB
    for (int i = threadIdx.x; i < 4096; i += 256) Wl[i] = W[i];
    __syncthreads();

    int lane = threadIdx.x & 63;
    int sub  = lane >> 3;
    int li   = lane & 7;
    float bv = bias[lane];
    const uint4* x4 = (const uint4*)zin;

    int wid = (blockIdx.x * 256 + threadIdx.x) >> 6;
    int nw  = (gridDim.x * 256) >> 6;

    int ro = 0, cnt = 0, idx = 0;
    if (wid < N) {
        ro = row_offs[wid];
        cnt = deg[wid];
        if (lane < min(cnt, 64)) idx = cols[ro + lane];
    }
    for (int node = wid; node < N; node += nw) {
        int nnode = node + nw;
        int nro = 0, ncnt = 0;
        if (nnode < N) { nro = row_offs[nnode]; ncnt = deg[nnode]; }  // prefetch

        float av[8] = {0.f,0.f,0.f,0.f,0.f,0.f,0.f,0.f};
        int cc = 0;
        int cidx = idx;
        while (cc < cnt) {
            int m = min(cnt - cc, 64);
            for (int i = 0; i < m; i += 32) {
                int e1 = i + sub, e2 = i + 8 + sub, e3 = i + 16 + sub, e4 = i + 24 + sub;
                int s1 = __shfl(cidx, min(e1, m - 1));
                int s2 = __shfl(cidx, min(e2, m - 1));
                int s3 = __shfl(cidx, min(e3, m - 1));
                int s4 = __shfl(cidx, min(e4, m - 1));
                uint4 v1 = make_uint4(0u,0u,0u,0u), v2 = v1, v3 = v1, v4 = v1;
                if (e1 < m) v1 = x4[(size_t)s1 * 8 + li];
                if (e2 < m) v2 = x4[(size_t)s2 * 8 + li];
                if (e3 < m) v3 = x4[(size_t)s3 * 8 + li];
                if (e4 < m) v4 = x4[(size_t)s4 * 8 + li];
                av[0] += bflo(v1.x); av[1] += bfhi(v1.x);
                av[2] += bflo(v1.y); av[3] += bfhi(v1.y);
                av[4] += bflo(v1.z); av[5] += bfhi(v1.z);
                av[6] += bflo(v1.w); av[7] += bfhi(v1.w);
                av[0] += bflo(v2.x); av[1] += bfhi(v2.x);
                av[2] += bflo(v2.y); av[3] += bfhi(v2.y);
                av[4] += bflo(v2.z); av[5] += bfhi(v2.z);
                av[6] += bflo(v2.w); av[7] += bfhi(v2.w);
                av[0] += bflo(v3.x); av[1] += bfhi(v3.x);
                av[2] += bflo(v3.y); av[3] += bfhi(v3.y);
                av[4] += bflo(v3.z); av[5] += bfhi(v3.z);
                av[6] += bflo(v3.w); av[7] += bfhi(v3.w);
                av[0] += bflo(v4.x); av[1] += bfhi(v4.x);
                av[2] += bflo(v4.y); av[3] += bfhi(v4.y);
                av[4] += bflo(v4.z); av[5] += bfhi(v4.z);
                av[6] += bflo(v4.w); av[7] += bfhi(v4.w);
            }
            cc += 64;
            if (cc < cnt) cidx = (lane < min(cnt - cc, 64)) ? cols[ro + cc + lane] : 0;
        }
        // prefetch next node's col during the reduce
        idx = 0;
        if (nnode < N && lane < min(ncnt, 64)) idx = cols[nro + lane];

        #pragma unroll
        for (int off = 8; off <= 32; off <<= 1) {
            #pragma unroll
            for (int r = 0; r < 8; r++) av[r] += __shfl_xor(av[r], off);
        }
        // all 64 lanes now hold the full aggregated row: s[li*8+r] = av[r],
        // replicated across subs. Lane kb (0..7) has li==kb.
        // GEMV: zv = sum_k s[k] * W[k][lane]
        float zv = 0.f;
        for (int kb = 0; kb < 8; kb++) {               // runtime loop: <=8 live W vals
            #pragma unroll
            for (int r = 0; r < 8; r++) {
                float sk = __shfl(av[r], kb);          // s[kb*8+r]
                zv += sk * Wl[(kb * 8 + r) * 64 + lane]; // lane-strided: conflict-free
            }
        }
        float nd = ndst[node];
        zv = fmaxf(nd * zv + bv, 0.f);
        if (MODE == 0) {
            zv *= nsrc[node];                          // prescale for layer-2 agg
            int u = (int)f2bf(zv);
            int o = u | (__shfl_down(u, 1) << 16);
            if (!(lane & 1))                           // 32 lanes, 128B coalesced
                ((unsigned*)yout)[(size_t)node * 32 + (lane >> 1)] = (unsigned)o;
        } else {
            int g = gids[node];                        // mean_nodes via atomics
            atomicAdd(&gacc[(size_t)g * 64 + lane], zv);
        }
        ro = nro; cnt = ncnt;
    }
}

// --- per-graph mean + 64x5 classifier (1 wave per graph) -------------------
__global__ __launch_bounds__(64) void cls_kernel(
    const float* __restrict__ gacc, const int* __restrict__ goffs,
    const float* __restrict__ Wc, const float* __restrict__ bc,
    float* __restrict__ out, int G)
{
    int g = blockIdx.x;
    int lane = threadIdx.x;
    float cnt = (float)max(goffs[g + 1] - goffs[g], 1);
    float mean = gacc[(size_t)g * 64 + lane] / cnt;
    #pragma unroll
    for (int c = 0; c < 5; c++) {
        float p = mean * Wc[lane * 5 + c];
        #pragma unroll
        for (int off = 32; off; off >>= 1) p += __shfl_down(p, off);
        if (lane == 0) out[g * 5 + c] = p + bc[c];
    }
}

extern "C" void kernel_launch(void* const* d_in, const int* in_sizes, int n_in,
                              void* d_out, int out_size, void* d_ws, size_t ws_size,
                              hipStream_t stream)
{
    const float* h    = (const float*)d_in[0];
    const int*   src  = (const int*)d_in[1];
    const int*   dst  = (const int*)d_in[2];
    const int*   gids = (const int*)d_in[3];
    const float* W1   = (const float*)d_in[4];
    const float* b1   = (const float*)d_in[5];
    const float* W2   = (const float*)d_in[6];
    const float* b2   = (const float*)d_in[7];
    const float* Wc   = (const float*)d_in[8];
    const float* bc   = (const float*)d_in[9];
    float* out = (float*)d_out;

    const int N = in_sizes[0] / 64;
    const int E = in_sizes[1];
    const int G = out_size / 5;
    const int NB = (N + 511) >> 9;
    const int NBB = (N + 255) / 256;        // bounds blocks

    auto align = [](size_t x) { return (x + 255) & ~(size_t)255; };
    char* p = (char*)d_ws;
    // curD | curS | gacc contiguous -> single memset clears all three
    int* curD    = (int*)p;
    int* curS    = curD + NBK;
    float* gacc  = (float*)(p + (size_t)2 * NBK * 4);   // G*64 floats
    size_t zbytes = (size_t)2 * NBK * 4 + (size_t)G * 64 * 4;
    p += align(zbytes);
    int* row_offs= (int*)p;            p += align((size_t)N * 4);
    int* deg     = (int*)p;            p += align((size_t)N * 4);
    float* nsrc  = (float*)p;          p += align((size_t)N * 4);
    float* ndst  = (float*)p;          p += align((size_t)N * 4);
    int* goffs   = (int*)p;            p += align((size_t)(G + 1) * 4);
    int* pack    = (int*)p;            p += align((size_t)NBK * CAP * 4);
    unsigned short* sloc = (unsigned short*)p; p += align((size_t)NBK * CAP * 2);
    int* cols    = (int*)p;            p += align((size_t)NBK * CAP * 4);
    unsigned short* xs  = (unsigned short*)p; p += align((size_t)N * 64 * 2);
    unsigned short* h1s = (unsigned short*)p; p += align((size_t)N * 64 * 2);

    hipMemsetAsync(curD, 0, zbytes, stream);

    pA_scatter<<<HB + NBB, 256, 0, stream>>>(src, dst, curD, curS, pack, sloc,
                                             gids, goffs, E, NB, N, G);
    p5_build<<<2 * NB, 256, 0, stream>>>(pack, sloc, curD, curS, cols,
                                         row_offs, deg, nsrc, ndst, h, xs, N, NB);

    agg_gemv<0><<<4096, 256, 0, stream>>>(xs, h1s, cols, row_offs, deg,
                                          W1, b1, ndst, nsrc, nullptr, nullptr, N);
    agg_gemv<1><<<4096, 256, 0, stream>>>(h1s, nullptr, cols, row_offs, deg,
                                          W2, b2, ndst, nullptr, gids, gacc, N);
    cls_kernel<<<G, 64, 0, stream>>>(gacc, goffs, Wc, bc, out, G);
}

// Round 3
// 274.549 us; speedup vs baseline: 2.3871x; 1.2304x over previous
//
#include <hip/hip_runtime.h>
#include <hip/hip_bf16.h>

// ---------------------------------------------------------------------------
// 2-layer GraphConv (DGL norm='both') + mean_nodes pool + linear classifier.
// N=80000, E=1.28M, D=H=64, C=5, G=512.
// R14: R13's fused agg+GEMV was LDS-PIPE-BOUND: 64 ds_bpermute + 64
// ds_read_b32 per node = 128 LDS ops/node -> 80000/256CU*152*5.8cyc = 114us
// (matches 107us measured; VALU 29%, HBM 10%, conflicts 0 -- nothing else
// busy). Fix: GEMV with ZERO LDS traffic:
//  (a) W held in 64 per-lane VGPRs: lane (s,li) preloads W[8li+r][8s+j]
//      (any LDS layout has unavoidable 8-16-way conflicts here: the 8 s-lanes
//      alias mod-32 banks because the row stride is 0 mod 32);
//  (b) lane computes its own 8x8 partial (64 FMA, inputs lane-local after the
//      existing 24-shfl butterfly), then a 3-step reduce-scatter over the li
//      bits (4+2+1 = 7 shfls) lands z[lane] directly.
// LDS ops/node: 152 -> 31 => epilogue ~31us/CU, back under the gather floor.
// pA_scatter / p5_build / cls unchanged (R11-verbatim).
// ---------------------------------------------------------------------------

#define NBK 160            // max buckets: ceil(80000/512)=157 <= 160
#define HB  256            // edge-pass blocks in pA
#define CAP 9216           // per-bucket slot capacity (mean 8192, +11 sigma)

typedef __attribute__((ext_vector_type(8))) short bf16x8;
typedef __attribute__((ext_vector_type(4))) float f32x4;

__device__ __forceinline__ float bflo(unsigned u) { return __uint_as_float(u << 16); }
__device__ __forceinline__ float bfhi(unsigned u) { return __uint_as_float(u & 0xffff0000u); }
__device__ __forceinline__ float bf1(unsigned short u) { return __uint_as_float((unsigned)u << 16); }
__device__ __forceinline__ unsigned short f2bf(float f) {   // RNE
    unsigned u = __float_as_uint(f);
    return (unsigned short)((u + 0x7fff + ((u >> 16) & 1)) >> 16);
}

// --- pA: single-pass bucket scatter (blocks < HB) + graph bounds (rest) ----
__global__ __launch_bounds__(256) void pA_scatter(
    const int* __restrict__ src, const int* __restrict__ dst,
    int* __restrict__ curD, int* __restrict__ curS,       // NBK cursors each, pre-zeroed
    int* __restrict__ pack, unsigned short* __restrict__ sloc,
    const int* __restrict__ gids, int* __restrict__ goffs,
    int E, int NB, int N, int G)
{
    if (blockIdx.x >= HB) {                  // fused bounds_kernel
        int i = (blockIdx.x - HB) * 256 + threadIdx.x;
        if (i >= N) return;
        int b = gids[i];
        if (i == 0) {
            for (int g = 0; g <= b; g++) goffs[g] = 0;
        } else {
            int a = gids[i - 1];
            for (int g = a + 1; g <= b; g++) goffs[g] = i;
        }
        if (i == N - 1) {
            for (int g = b + 1; g <= G; g++) goffs[g] = N;
        }
        return;
    }
    __shared__ int hd[NBK], hs[NBK];
    int t = threadIdx.x;
    for (int i = t; i < NB; i += 256) { hd[i] = 0; hs[i] = 0; }
    __syncthreads();
    int chunk = (E + HB - 1) / HB;
    int s0 = blockIdx.x * chunk, s1 = min(E, s0 + chunk);
    // vectorized histogram pass
    int q0 = s0 >> 2, q1 = s1 >> 2;          // s0 is 4-aligned (chunk%4==0)
    const int4* s4 = (const int4*)src;
    const int4* d4 = (const int4*)dst;
    for (int q = q0 + t; q < q1; q += 256) {
        int4 d = d4[q];
        int4 s = s4[q];
        atomicAdd(&hd[d.x >> 9], 1); atomicAdd(&hd[d.y >> 9], 1);
        atomicAdd(&hd[d.z >> 9], 1); atomicAdd(&hd[d.w >> 9], 1);
        atomicAdd(&hs[s.x >> 9], 1); atomicAdd(&hs[s.y >> 9], 1);
        atomicAdd(&hs[s.z >> 9], 1); atomicAdd(&hs[s.w >> 9], 1);
    }
    for (int i = (q1 << 2) + t; i < s1; i += 256) {   // tail
        atomicAdd(&hd[dst[i] >> 9], 1);
        atomicAdd(&hs[src[i] >> 9], 1);
    }
    __syncthreads();
    for (int b = t; b < NB; b += 256) {      // reserve global slots
        int cd = hd[b], cs = hs[b];
        hd[b] = cd ? atomicAdd(&curD[b], cd) : 0;   // device atomic, 1/bucket
        hs[b] = cs ? atomicAdd(&curS[b], cs) : 0;
    }
    __syncthreads();
    // vectorized scatter pass (chunk re-read is L2-hot)
    for (int q = q0 + t; q < q1; q += 256) {
        int4 d = d4[q];
        int4 s = s4[q];
        #pragma unroll
        for (int j = 0; j < 4; j++) {
            int ss = j == 0 ? s.x : j == 1 ? s.y : j == 2 ? s.z : s.w;
            int dd = j == 0 ? d.x : j == 1 ? d.y : j == 2 ? d.z : d.w;
            int bd = dd >> 9, bs = ss >> 9;
            int pd = atomicAdd(&hd[bd], 1);  // LDS atomic
            int ps = atomicAdd(&hs[bs], 1);  // LDS atomic
            if (pd < CAP) pack[(size_t)bd * CAP + pd] = ((dd & 511) << 17) | ss;
            if (ps < CAP) sloc[(size_t)bs * CAP + ps] = (unsigned short)(ss & 511);
        }
    }
    for (int i = (q1 << 2) + t; i < s1; i += 256) {   // tail
        int s = src[i], d = dst[i];
        int bd = d >> 9, bs = s >> 9;
        int pd = atomicAdd(&hd[bd], 1);
        int ps = atomicAdd(&hs[bs], 1);
        if (pd < CAP) pack[(size_t)bd * CAP + pd] = ((d & 511) << 17) | s;
        if (ps < CAP) sloc[(size_t)bs * CAP + ps] = (unsigned short)(s & 511);
    }
}

// --- p5: dst mode -> CSR (row_offs,deg,col,ndst); src mode -> nsrc+prescale -
__global__ __launch_bounds__(256) void p5_build(
    const int* __restrict__ pack, const unsigned short* __restrict__ sloc,
    const int* __restrict__ curD, const int* __restrict__ curS,
    int* __restrict__ col, int* __restrict__ row_offs, int* __restrict__ deg,
    float* __restrict__ nsrc, float* __restrict__ ndst,
    const float* __restrict__ h, unsigned short* __restrict__ xs,
    int N, int NB)
{
    __shared__ int hist[512];
    __shared__ float nsl[512];
    __shared__ int wt[4];
    int t = threadIdx.x;
    bool dmode = blockIdx.x < NB;
    int b = dmode ? blockIdx.x : blockIdx.x - NB;
    int n0 = b << 9, n1 = min(N, n0 + 512);
    hist[t] = 0; hist[t + 256] = 0;
    __syncthreads();
    int e0 = b * CAP;
    int tot = min(dmode ? curD[b] : curS[b], CAP);
    int e1 = e0 + tot;
    if (!dmode) {
        for (int i = e0 + t; i < e1; i += 256)
            atomicAdd(&hist[sloc[i]], 1);            // LDS atomic
        __syncthreads();
        for (int n = n0 + t; n < n1; n += 256) {
            float s = rsqrtf((float)max(hist[n - n0], 1));
            nsrc[n] = s;
            nsl[n - n0] = s;
        }
        __syncthreads();
        int cnt = n1 - n0;
        const float2* h2p = (const float2*)h;
        ushort2* xp = (ushort2*)xs;
        for (int i = t; i < cnt * 32; i += 256) {
            int node = i >> 5;
            float s = nsl[node];
            float2 v = h2p[(size_t)(n0 + node) * 32 + (i & 31)];
            ushort2 o;
            o.x = f2bf(v.x * s);
            o.y = f2bf(v.y * s);
            xp[(size_t)(n0 + node) * 32 + (i & 31)] = o;
        }
        return;
    }
    for (int i = e0 + t; i < e1; i += 256)
        atomicAdd(&hist[pack[i] >> 17], 1);          // LDS atomic
    __syncthreads();
    int c0 = hist[2 * t], c1 = hist[2 * t + 1];
    int v = c0 + c1;
    int lane = t & 63, w = t >> 6;
    int x = v;
    #pragma unroll
    for (int off = 1; off < 64; off <<= 1) {
        int y = __shfl_up(x, off);
        if (lane >= off) x += y;
    }
    if (lane == 63) wt[w] = x;
    __syncthreads();
    int bw = 0;
    for (int i = 0; i < w; i++) bw += wt[i];
    int excl = x - v + bw;
    int n = n0 + 2 * t;
    if (n < n1) {
        row_offs[n] = e0 + excl;
        deg[n] = c0;
        ndst[n] = rsqrtf((float)max(c0, 1));
    }
    if (n + 1 < n1) {
        row_offs[n + 1] = e0 + excl + c0;
        deg[n + 1] = c1;
        ndst[n + 1] = rsqrtf((float)max(c1, 1));
    }
    hist[2 * t] = excl;
    hist[2 * t + 1] = excl + c0;
    __syncthreads();
    for (int i = e0 + t; i < e1; i += 256) {
        int wd = pack[i];
        int pos = atomicAdd(&hist[wd >> 17], 1);     // LDS atomic
        col[e0 + pos] = wd & 0x1FFFF;
    }
}

// --- fused gather-sum + row-local 64x64 GEMV epilogue (W in registers) -----
// MODE 0: yout[node] = bf16(relu(nd*(s@W)+b) * ns)       (layer 1)
// MODE 1: atomicAdd(gacc[gids[node]], relu(nd*(s@W)+b))  (layer 2 + pool)
template<int MODE>
__global__ __launch_bounds__(256) void agg_gemv(
    const unsigned short* __restrict__ zin, unsigned short* __restrict__ yout,
    const int* __restrict__ cols, const int* __restrict__ row_offs,
    const int* __restrict__ deg, const float* __restrict__ W,
    const float* __restrict__ bias, const float* __restrict__ ndst,
    const float* __restrict__ nsrc, const int* __restrict__ gids,
    float* __restrict__ gacc, int N)
{
    int lane = threadIdx.x & 63;
    int sub  = lane >> 3;
    int li   = lane & 7;
    float bv = bias[lane];

    // per-lane W fragment: wreg[r][j] = W[8*li+r][8*sub+j]  (64 VGPRs, f32)
    float wreg[8][8];
    {
        const float4* w4 = (const float4*)W;
        #pragma unroll
        for (int r = 0; r < 8; r++) {
            float4 lo = w4[(8 * li + r) * 16 + 2 * sub];
            float4 hi = w4[(8 * li + r) * 16 + 2 * sub + 1];
            wreg[r][0] = lo.x; wreg[r][1] = lo.y; wreg[r][2] = lo.z; wreg[r][3] = lo.w;
            wreg[r][4] = hi.x; wreg[r][5] = hi.y; wreg[r][6] = hi.z; wreg[r][7] = hi.w;
        }
    }

    const uint4* x4 = (const uint4*)zin;

    int wid = (blockIdx.x * 256 + threadIdx.x) >> 6;
    int nw  = (gridDim.x * 256) >> 6;

    int ro = 0, cnt = 0, idx = 0;
    if (wid < N) {
        ro = row_offs[wid];
        cnt = deg[wid];
        if (lane < min(cnt, 64)) idx = cols[ro + lane];
    }
    for (int node = wid; node < N; node += nw) {
        int nnode = node + nw;
        int nro = 0, ncnt = 0;
        if (nnode < N) { nro = row_offs[nnode]; ncnt = deg[nnode]; }  // prefetch

        float av[8] = {0.f,0.f,0.f,0.f,0.f,0.f,0.f,0.f};
        int cc = 0;
        int cidx = idx;
        while (cc < cnt) {
            int m = min(cnt - cc, 64);
            for (int i = 0; i < m; i += 32) {
                int e1 = i + sub, e2 = i + 8 + sub, e3 = i + 16 + sub, e4 = i + 24 + sub;
                int s1 = __shfl(cidx, min(e1, m - 1));
                int s2 = __shfl(cidx, min(e2, m - 1));
                int s3 = __shfl(cidx, min(e3, m - 1));
                int s4 = __shfl(cidx, min(e4, m - 1));
                uint4 v1 = make_uint4(0u,0u,0u,0u), v2 = v1, v3 = v1, v4 = v1;
                if (e1 < m) v1 = x4[(size_t)s1 * 8 + li];
                if (e2 < m) v2 = x4[(size_t)s2 * 8 + li];
                if (e3 < m) v3 = x4[(size_t)s3 * 8 + li];
                if (e4 < m) v4 = x4[(size_t)s4 * 8 + li];
                av[0] += bflo(v1.x); av[1] += bfhi(v1.x);
                av[2] += bflo(v1.y); av[3] += bfhi(v1.y);
                av[4] += bflo(v1.z); av[5] += bfhi(v1.z);
                av[6] += bflo(v1.w); av[7] += bfhi(v1.w);
                av[0] += bflo(v2.x); av[1] += bfhi(v2.x);
                av[2] += bflo(v2.y); av[3] += bfhi(v2.y);
                av[4] += bflo(v2.z); av[5] += bfhi(v2.z);
                av[6] += bflo(v2.w); av[7] += bfhi(v2.w);
                av[0] += bflo(v3.x); av[1] += bfhi(v3.x);
                av[2] += bflo(v3.y); av[3] += bfhi(v3.y);
                av[4] += bflo(v3.z); av[5] += bfhi(v3.z);
                av[6] += bflo(v3.w); av[7] += bfhi(v3.w);
                av[0] += bflo(v4.x); av[1] += bfhi(v4.x);
                av[2] += bflo(v4.y); av[3] += bfhi(v4.y);
                av[4] += bflo(v4.z); av[5] += bfhi(v4.z);
                av[6] += bflo(v4.w); av[7] += bfhi(v4.w);
            }
            cc += 64;
            if (cc < cnt) cidx = (lane < min(cnt - cc, 64)) ? cols[ro + cc + lane] : 0;
        }
        // prefetch next node's col during the reduce
        idx = 0;
        if (nnode < N && lane < min(ncnt, 64)) idx = cols[nro + lane];

        // butterfly over subs: av[r] -> full s[8*li+r] in every lane
        #pragma unroll
        for (int off = 8; off <= 32; off <<= 1) {
            #pragma unroll
            for (int r = 0; r < 8; r++) av[r] += __shfl_xor(av[r], off);
        }

        // GEMV, all lane-local: partial z for cols 8*sub+j over k-block li
        float pz[8];
        #pragma unroll
        for (int j = 0; j < 8; j++) {
            float acc = 0.f;
            #pragma unroll
            for (int r = 0; r < 8; r++) acc = fmaf(av[r], wreg[r][j], acc);
            pz[j] = acc;
        }
        // reduce-scatter over li bits: lane ends with z[8*sub+li] = z[lane]
        float q4[4];
        {
            int bit = lane & 1;
            #pragma unroll
            for (int p = 0; p < 4; p++) {
                float mine  = bit ? pz[2 * p + 1] : pz[2 * p];
                float yours = bit ? pz[2 * p]     : pz[2 * p + 1];
                q4[p] = mine + __shfl_xor(yours, 1);
            }
        }
        float q2[2];
        {
            int bit = (lane >> 1) & 1;
            #pragma unroll
            for (int p = 0; p < 2; p++) {
                float mine  = bit ? q4[2 * p + 1] : q4[2 * p];
                float yours = bit ? q4[2 * p]     : q4[2 * p + 1];
                q2[p] = mine + __shfl_xor(yours, 2);
            }
        }
        float zv;
        {
            int bit = (lane >> 2) & 1;
            float mine  = bit ? q2[1] : q2[0];
            float yours = bit ? q2[0] : q2[1];
            zv = mine + __shfl_xor(yours, 4);
        }

        float nd = ndst[node];
        zv = fmaxf(nd * zv + bv, 0.f);
        if (MODE == 0) {
            zv *= nsrc[node];                          // prescale for layer-2 agg
            int u = (int)f2bf(zv);
            int o = u | (__shfl_down(u, 1) << 16);
            if (!(lane & 1))                           // 32 lanes, 128B coalesced
                ((unsigned*)yout)[(size_t)node * 32 + (lane >> 1)] = (unsigned)o;
        } else {
            int g = gids[node];                        // mean_nodes via atomics
            atomicAdd(&gacc[(size_t)g * 64 + lane], zv);
        }
        ro = nro; cnt = ncnt;
    }
}

// --- per-graph mean + 64x5 classifier (1 wave per graph) -------------------
__global__ __launch_bounds__(64) void cls_kernel(
    const float* __restrict__ gacc, const int* __restrict__ goffs,
    const float* __restrict__ Wc, const float* __restrict__ bc,
    float* __restrict__ out, int G)
{
    int g = blockIdx.x;
    int lane = threadIdx.x;
    float cnt = (float)max(goffs[g + 1] - goffs[g], 1);
    float mean = gacc[(size_t)g * 64 + lane] / cnt;
    #pragma unroll
    for (int c = 0; c < 5; c++) {
        float p = mean * Wc[lane * 5 + c];
        #pragma unroll
        for (int off = 32; off; off >>= 1) p += __shfl_down(p, off);
        if (lane == 0) out[g * 5 + c] = p + bc[c];
    }
}

extern "C" void kernel_launch(void* const* d_in, const int* in_sizes, int n_in,
                              void* d_out, int out_size, void* d_ws, size_t ws_size,
                              hipStream_t stream)
{
    const float* h    = (const float*)d_in[0];
    const int*   src  = (const int*)d_in[1];
    const int*   dst  = (const int*)d_in[2];
    const int*   gids = (const int*)d_in[3];
    const float* W1   = (const float*)d_in[4];
    const float* b1   = (const float*)d_in[5];
    const float* W2   = (const float*)d_in[6];
    const float* b2   = (const float*)d_in[7];
    const float* Wc   = (const float*)d_in[8];
    const float* bc   = (const float*)d_in[9];
    float* out = (float*)d_out;

    const int N = in_sizes[0] / 64;
    const int E = in_sizes[1];
    const int G = out_size / 5;
    const int NB = (N + 511) >> 9;
    const int NBB = (N + 255) / 256;        // bounds blocks

    auto align = [](size_t x) { return (x + 255) & ~(size_t)255; };
    char* p = (char*)d_ws;
    // curD | curS | gacc contiguous -> single memset clears all three
    int* curD    = (int*)p;
    int* curS    = curD + NBK;
    float* gacc  = (float*)(p + (size_t)2 * NBK * 4);   // G*64 floats
    size_t zbytes = (size_t)2 * NBK * 4 + (size_t)G * 64 * 4;
    p += align(zbytes);
    int* row_offs= (int*)p;            p += align((size_t)N * 4);
    int* deg     = (int*)p;            p += align((size_t)N * 4);
    float* nsrc  = (float*)p;          p += align((size_t)N * 4);
    float* ndst  = (float*)p;          p += align((size_t)N * 4);
    int* goffs   = (int*)p;            p += align((size_t)(G + 1) * 4);
    int* pack    = (int*)p;            p += align((size_t)NBK * CAP * 4);
    unsigned short* sloc = (unsigned short*)p; p += align((size_t)NBK * CAP * 2);
    int* cols    = (int*)p;            p += align((size_t)NBK * CAP * 4);
    unsigned short* xs  = (unsigned short*)p; p += align((size_t)N * 64 * 2);
    unsigned short* h1s = (unsigned short*)p; p += align((size_t)N * 64 * 2);

    hipMemsetAsync(curD, 0, zbytes, stream);

    pA_scatter<<<HB + NBB, 256, 0, stream>>>(src, dst, curD, curS, pack, sloc,
                                             gids, goffs, E, NB, N, G);
    p5_build<<<2 * NB, 256, 0, stream>>>(pack, sloc, curD, curS, cols,
                                         row_offs, deg, nsrc, ndst, h, xs, N, NB);

    agg_gemv<0><<<4096, 256, 0, stream>>>(xs, h1s, cols, row_offs, deg,
                                          W1, b1, ndst, nsrc, nullptr, nullptr, N);
    agg_gemv<1><<<4096, 256, 0, stream>>>(h1s, nullptr, cols, row_offs, deg,
                                          W2, b2, ndst, nullptr, gids, gacc, N);
    cls_kernel<<<G, 64, 0, stream>>>(gacc, goffs, Wc, bc, out, G);
}